// Round 1
// baseline (356.273 us; speedup 1.0000x reference)
//
#include <hip/hip_runtime.h>
#include <hip/hip_cooperative_groups.h>
#include <stdint.h>

namespace cg = cooperative_groups;

#define Bn 4
#define An 3
#define Hn 168
#define Wn 256
#define Mn 32
#define HWn (Hn*Wn)
#define Nn (HWn*An)          // 129024
#define POS_CAP 8192
#define BND_CAP 2048
#define NPERIM 256
#define NPOSMAX 128
#define FG_THR 0.7f
#define BG_THR 0.3f
#define BETA (1.0f/9.0f)

#define NBLK 126             // blocks per image
#define APT 4                // anchors/thread (measured best)
#define STRIDE (NBLK * 256)  // 32256
#define SEG 1024             // private negative segment per block

// ---- workspace layout (uint32 word offsets) ----
#define OFF_POSCNT 0            // Bn
#define OFF_BNDCNT 4            // Bn
#define OFF_BOUND  8            // Bn (int32, -1 = all negatives selected)
#define OFF_NEED   12           // Bn
#define OFF_COUNT  16           // 1
#define OFF_CLS    17           // 1 (float bits)
#define OFF_REG    18           // 1 (float bits)
#define OFF_DONE   19           // 1
#define OFF_KEYS   24           // Bn*2                       -> 32
#define OFF_PCM    32           // Bn*NBLK*Mn = 16128         -> 16160 (block colmax bits)
#define OFF_NSEGC  16160        // Bn*NBLK = 504              -> 16664
#define OFF_PLIST  16664        // Bn*POS_CAP*2 = 65536       -> 82200
#define OFF_BLIST  82200        // Bn*BND_CAP*2 = 16384       -> 98584
#define OFF_NLIST  98584        // Bn*NBLK*SEG*2 = 1032192    -> 1130776 (~4.1MB)
#define OFF_WPCM   1130776      // Bn*NBLK*4*Mn = 64512       -> 1195288 (wave colmax bits)
#define OFF_GHIST  1195288      // Bn*1024 = 4096             -> 1199384 (global hist)

// ------------------- threefry2x32 (20 rounds) -------------------
__device__ __forceinline__ uint32_t rotl32(uint32_t v, int n) { return (v << n) | (v >> (32 - n)); }

__device__ __forceinline__ void tf2x32(uint32_t k0, uint32_t k1, uint32_t x0, uint32_t x1,
                                       uint32_t& o0, uint32_t& o1) {
    uint32_t k2 = k0 ^ k1 ^ 0x1BD11BDAu;
    x0 += k0; x1 += k1;
    x0 += x1; x1 = rotl32(x1, 13); x1 ^= x0;
    x0 += x1; x1 = rotl32(x1, 15); x1 ^= x0;
    x0 += x1; x1 = rotl32(x1, 26); x1 ^= x0;
    x0 += x1; x1 = rotl32(x1, 6);  x1 ^= x0;
    x0 += k1; x1 += k2 + 1u;
    x0 += x1; x1 = rotl32(x1, 17); x1 ^= x0;
    x0 += x1; x1 = rotl32(x1, 29); x1 ^= x0;
    x0 += x1; x1 = rotl32(x1, 16); x1 ^= x0;
    x0 += x1; x1 = rotl32(x1, 24); x1 ^= x0;
    x0 += k2; x1 += k0 + 2u;
    x0 += x1; x1 = rotl32(x1, 13); x1 ^= x0;
    x0 += x1; x1 = rotl32(x1, 15); x1 ^= x0;
    x0 += x1; x1 = rotl32(x1, 26); x1 ^= x0;
    x0 += x1; x1 = rotl32(x1, 6);  x1 ^= x0;
    x0 += k0; x1 += k1 + 3u;
    x0 += x1; x1 = rotl32(x1, 17); x1 ^= x0;
    x0 += x1; x1 = rotl32(x1, 29); x1 ^= x0;
    x0 += x1; x1 = rotl32(x1, 16); x1 ^= x0;
    x0 += x1; x1 = rotl32(x1, 24); x1 ^= x0;
    x0 += k1; x1 += k2 + 4u;
    x0 += x1; x1 = rotl32(x1, 13); x1 ^= x0;
    x0 += x1; x1 = rotl32(x1, 15); x1 ^= x0;
    x0 += x1; x1 = rotl32(x1, 26); x1 ^= x0;
    x0 += x1; x1 = rotl32(x1, 6);  x1 ^= x0;
    x0 += k2; x1 += k0 + 5u;
    o0 = x0; o1 = x1;
}

__device__ __forceinline__ uint32_t rng_m23(uint32_t k0, uint32_t k1, uint32_t i) {
    uint32_t o0, o1;
    tf2x32(k0, k1, 0u, i, o0, o1);
    return (o0 ^ o1) >> 9;
}

// ------------------- IoU (single definition -> bit-identical everywhere) ------------
__device__ __forceinline__ float iou_one(float a0, float a1, float a2, float a3,
                                         float t0, float t1, float t2, float t3) {
    float xtl = fmaxf(a0, t0), ytl = fmaxf(a1, t1);
    float xrb = fminf(a2, t2), yrb = fminf(a3, t3);
    float iw = fmaxf(xrb - xtl + 1.0f, 0.0f);
    float ih = fmaxf(yrb - ytl + 1.0f, 0.0f);
    float inter = iw * ih;
    float area1 = (a2 - a0 + 1.0f) * (a3 - a1 + 1.0f);
    float area2 = (t2 - t0 + 1.0f) * (t3 - t1 + 1.0f);
    return inter * __builtin_amdgcn_rcpf(area1 + area2 - inter);
}

// ------------------- selection order (JAX top_k: larger priority first, tie -> smaller idx)
__device__ __forceinline__ bool sel_less(uint2 a, uint2 b) {
    return (a.x > b.x) || (a.x == b.x && a.y < b.y);
}

__device__ void bitonic_sort_shared(uint2* buf, int n) {   // n = pow2
    for (int k = 2; k <= n; k <<= 1) {
        for (int j = k >> 1; j > 0; j >>= 1) {
            for (int t = (int)threadIdx.x; t < n; t += 256) {
                int ixj = t ^ j;
                if (ixj > t) {
                    uint2 x = buf[t], y = buf[ixj];
                    bool up = ((t & k) == 0);
                    bool sw = up ? sel_less(y, x) : sel_less(x, y);
                    if (sw) { buf[t] = y; buf[ixj] = x; }
                }
            }
            __syncthreads();
        }
    }
}

// ------------------- shared-memory union (max 17.4 KB) -------------------
struct ShP1 { float part[4][Mn]; };
struct ShP2 { float cmf[Mn]; float redf[256]; uint32_t lh[1024]; uint32_t segcnt; };
struct ShP3 { uint32_t csum[256]; };
struct ShP45 { uint2 buf[BND_CAP]; float red[256]; };
union ShU { ShP1 p1; ShP2 p2; ShP3 p3; ShP45 p45; };

// =====================================================================================
// Single cooperative kernel: 5 phases separated by grid.sync().
// Per-anchor state (anchor coords, rowmax, argmax, tie-mask vs wave colmax) lives in
// VGPRs across the first sync -> the old k2's full IoU recompute + anchor reload is gone.
// restore check: iou == global_cm  <=>  iou == wave_max  AND  wave_max == global_cm
// (exact: all three values come from identical fmaxf chains; max is assoc/comm).
// =====================================================================================
__global__ void __launch_bounds__(256, 2)
fused(const float* __restrict__ anchors, const float* __restrict__ targets,
      const float* __restrict__ sizes, const float* __restrict__ logits,
      const float* __restrict__ bregs, uint32_t* __restrict__ ws,
      float* __restrict__ out)
{
    cg::grid_group grid = cg::this_grid();
    __shared__ ShU smem;
    const int j = blockIdx.x, b = blockIdx.y, tid = threadIdx.x;
    const int wid = tid >> 6, lane = tid & 63;

    // ---- folded init (block 0,0): control words, RNG keys, global hist ----
    if (j == 0 && b == 0) {
        if (tid < 24) ws[tid] = 0u;
        for (int q = tid; q < Bn * 1024; q += 256) ws[OFF_GHIST + q] = 0u;
        if (tid == 0) {
            for (int bb = 0; bb < Bn; ++bb) {
                uint32_t o0, o1;
                tf2x32(0u, 42u, 0u, (uint32_t)bb, o0, o1);
                ws[OFF_KEYS + 2*bb] = o0; ws[OFF_KEYS + 2*bb + 1] = o1;
            }
        }
    }

    // ================= phase 1: IoU pass (rowmax/argmax/tie-mask + colmax) =================
    const int base = j * 256 + tid;
    float4 av[APT];
    #pragma unroll
    for (int k = 0; k < APT; ++k)
        av[k] = ((const float4*)anchors)[b * Nn + base + k * STRIDE];

    float rowmax[APT]; int ori[APT]; uint32_t tie[APT];
    #pragma unroll
    for (int k = 0; k < APT; ++k) { rowmax[k] = -1.0f; ori[k] = 0; tie[k] = 0u; }

    uint32_t* wp = ws + OFF_WPCM + ((((size_t)b * NBLK + j) * 4 + wid) << 5);

    #pragma unroll 4
    for (int t = 0; t < Mn; ++t) {
        float4 tv = ((const float4*)targets)[b * Mn + t];
        float io[APT];
        float m0 = 0.0f;
        #pragma unroll
        for (int k = 0; k < APT; ++k) {
            io[k] = iou_one(av[k].x, av[k].y, av[k].z, av[k].w, tv.x, tv.y, tv.z, tv.w);
            if (io[k] > rowmax[k]) { rowmax[k] = io[k]; ori[k] = t; }
            m0 = fmaxf(m0, io[k]);
        }
        #pragma unroll
        for (int o = 32; o > 0; o >>= 1) m0 = fmaxf(m0, __shfl_xor(m0, o, 64));
        if (lane == 0) {
            smem.p1.part[wid][t] = m0;                 // block-level colmax input
            wp[t] = __float_as_uint(m0);               // wave-level colmax (for eqmask)
        }
        #pragma unroll
        for (int k = 0; k < APT; ++k)
            tie[k] |= (io[k] == m0) ? (1u << t) : 0u;  // tie vs THIS wave's colmax
    }
    __syncthreads();
    if (tid < Mn) {
        float v = fmaxf(fmaxf(smem.p1.part[0][tid], smem.p1.part[1][tid]),
                        fmaxf(smem.p1.part[2][tid], smem.p1.part[3][tid]));
        ws[OFF_PCM + ((size_t)b * NBLK + j) * Mn + tid] = __float_as_uint(v);
    }

    grid.sync();

    // ================= phase 2: global colmax, categorize, RNG, compaction =================
    {
        int t = tid & 31, sub = tid >> 5;
        float acc = 0.0f;
        for (int jj = sub; jj < NBLK; jj += 8)
            acc = fmaxf(acc, __uint_as_float(ws[OFF_PCM + ((size_t)b * NBLK + jj) * Mn + t]));
        smem.p2.redf[tid] = acc;
        __syncthreads();
        if (sub == 0) {
            #pragma unroll
            for (int q = 1; q < 8; ++q) acc = fmaxf(acc, smem.p2.redf[t + 32 * q]);
            smem.p2.cmf[t] = acc;
        }
    }
    #pragma unroll
    for (int q = 0; q < 4; ++q) smem.p2.lh[tid + 256 * q] = 0u;
    if (tid == 0) smem.p2.segcnt = 0u;
    __syncthreads();

    uint32_t eqmask;   // bit t: this wave's colmax[t] == global colmax[t]
    {
        bool eq = (lane < Mn) ? (__uint_as_float(wp[lane]) == smem.p2.cmf[lane]) : false;
        eqmask = (uint32_t)__ballot(eq);
    }

    {
        const float szh = sizes[b * 2 + 0], szw = sizes[b * 2 + 1];
        const uint32_t key0 = ws[OFF_KEYS + 2 * b], key1 = ws[OFF_KEYS + 2 * b + 1];
        unsigned long long lt_mask = (lane == 63) ? 0x7FFFFFFFFFFFFFFFull
                                                  : ((1ull << lane) - 1ull);
        uint2* nseg = (uint2*)(ws + OFF_NLIST) + (size_t)(b * NBLK + j) * SEG;
        #pragma unroll
        for (int k = 0; k < APT; ++k) {
            int i = base + k * STRIDE;
            bool inside = (av[k].x >= 0.0f) && (av[k].y >= 0.0f) &&
                          (av[k].z <= szw - 1.0f) && (av[k].w <= szh - 1.0f);
            bool restore = (tie[k] & eqmask) != 0u;
            uint32_t cat = 0;
            if (inside) {
                if (restore || rowmax[k] >= FG_THR) cat = 2;
                else if (rowmax[k] < BG_THR) cat = 1;
            }
            uint32_t m = rng_m23(key0, key1, (uint32_t)i);
            // positives: global wave-aggregated ticket (rare -> negligible)
            unsigned long long pmask = __ballot(cat == 2u);
            if (pmask) {
                int leader = __ffsll((long long)pmask) - 1;
                uint32_t bb = 0;
                if (lane == leader) bb = atomicAdd(&ws[OFF_POSCNT + b], (uint32_t)__popcll(pmask));
                bb = __shfl(bb, leader, 64);
                if (cat == 2u) {
                    uint32_t p = bb + (uint32_t)__popcll(pmask & lt_mask);
                    if (p < POS_CAP)
                        ((uint2*)(ws + OFF_PLIST))[(size_t)b * POS_CAP + p] =
                            make_uint2(m, (uint32_t)i | ((uint32_t)ori[k] << 17));
                }
            }
            // negatives: LDS-counter segment compaction (zero global atomics)
            unsigned long long nmask = __ballot(cat == 1u);
            if (nmask) {
                int leader = __ffsll((long long)nmask) - 1;
                uint32_t bb = 0;
                if (lane == leader) bb = atomicAdd(&smem.p2.segcnt, (uint32_t)__popcll(nmask));
                bb = __shfl(bb, leader, 64);
                if (cat == 1u) {
                    uint32_t p = bb + (uint32_t)__popcll(nmask & lt_mask);
                    nseg[p] = make_uint2(m, (uint32_t)i);
                    atomicAdd(&smem.p2.lh[m >> 13], 1u);
                }
            }
        }
    }
    __syncthreads();
    {   // flush LDS hist straight into the per-image global hist (order-independent ints)
        uint32_t* gh = ws + OFF_GHIST + b * 1024;
        #pragma unroll
        for (int q = 0; q < 4; ++q) {
            uint32_t v = smem.p2.lh[tid + 256 * q];
            if (v) atomicAdd(&gh[tid + 256 * q], v);
        }
        if (tid == 0) ws[OFF_NSEGC + b * NBLK + j] = smem.p2.segcnt;
    }

    grid.sync();

    // ================= phase 3: suffix scan of global hist + boundary (1 block/image) =====
    if (j == 0) {
        uint4 h = ((const uint4*)(ws + OFF_GHIST + (size_t)b * 1024))[tid];
        uint32_t sum = h.x + h.y + h.z + h.w;
        smem.p3.csum[tid] = sum;
        __syncthreads();
        for (int off = 1; off < 256; off <<= 1) {
            uint32_t mine = smem.p3.csum[tid];
            uint32_t add = (tid + off < 256) ? smem.p3.csum[tid + off] : 0u;
            __syncthreads();
            smem.p3.csum[tid] = mine + add;
            __syncthreads();
        }
        uint32_t pc = ws[OFF_POSCNT + b];
        int num_pos = (pc < (uint32_t)NPOSMAX) ? (int)pc : NPOSMAX;
        int k_neg = NPERIM - num_pos;
        uint32_t total = smem.p3.csum[0];
        if ((int)total < k_neg) {
            if (tid == 0) {
                ws[OFF_BOUND + b] = 0xFFFFFFFFu;
                ws[OFF_NEED + b] = 0u;
                atomicAdd(&ws[OFF_COUNT], (uint32_t)(num_pos + (int)total));
            }
        } else {
            uint32_t incl = smem.p3.csum[tid];
            uint32_t next = (tid < 255) ? smem.p3.csum[tid + 1] : 0u;
            if ((int)incl >= k_neg && (int)next < k_neg) {
                int cum = (int)next;
                uint32_t hv[4] = { h.x, h.y, h.z, h.w };
                int boundary = -1, needed = 0;
                #pragma unroll
                for (int q = 3; q >= 0; --q) {
                    int c = (int)hv[q];
                    if (cum + c >= k_neg) { boundary = 4 * tid + q; needed = k_neg - cum; break; }
                    cum += c;
                }
                ws[OFF_BOUND + b] = (uint32_t)boundary;
                ws[OFF_NEED + b] = (uint32_t)needed;
                atomicAdd(&ws[OFF_COUNT], (uint32_t)(num_pos + k_neg));
            }
        }
    }

    grid.sync();

    // ================= phase 4: scan private negative segments ==========================
    {
        int bd = (int)(int32_t)ws[OFF_BOUND + b];                // uniform
        int cnt = (int)ws[OFF_NSEGC + b * NBLK + j];             // uniform
        const uint2* nsegr = (const uint2*)(ws + OFF_NLIST) + (size_t)(b * NBLK + j) * SEG;
        float local = 0.0f;
        for (int idx = tid; idx < cnt; idx += 256) {
            uint2 e = nsegr[idx];
            int bk = (int)(e.x >> 13);
            if (bk > bd) {
                int i = (int)e.y;
                int a = i % An, hw = i / An;
                float l = logits[(b * An + a) * HWn + hw];
                local += fmaxf(l, 0.0f) + log1pf(expf(-fabsf(l)));   // BCE(l,0)
            } else if (bk == bd) {
                uint32_t q = atomicAdd(&ws[OFF_BNDCNT + b], 1u);    // rare (~100/image)
                if (q < BND_CAP)
                    ((uint2*)(ws + OFF_BLIST))[(size_t)b * BND_CAP + q] = e;
            }
        }
        smem.p45.red[tid] = local;
        __syncthreads();
        for (int s = 128; s > 0; s >>= 1) {
            if (tid < s) smem.p45.red[tid] += smem.p45.red[tid + s];
            __syncthreads();
        }
        if (tid == 0 && smem.p45.red[0] != 0.0f)
            atomicAdd((float*)&ws[OFF_CLS], smem.p45.red[0]);
    }

    grid.sync();

    // ================= phase 5: finalize (1 block/image) ================================
    if (j != 0) return;
    {
        uint2* buf = smem.p45.buf;
        float* red = smem.p45.red;
        float cls = 0.0f, reg = 0.0f;

        uint32_t pcu = ws[OFF_POSCNT + b];
        int pc = (pcu < (uint32_t)POS_CAP) ? (int)pcu : POS_CAP;
        const uint2* plist = (const uint2*)(ws + OFF_PLIST) + (size_t)b * POS_CAP;
        int psel = (pc < NPOSMAX) ? pc : NPOSMAX;
        bool use_buf = false;
        if (pc > NPOSMAX) {
            int n = (pc < BND_CAP) ? pc : BND_CAP;
            for (int t = tid; t < n; t += 256) buf[t] = plist[t];
            int npad = 1; while (npad < n) npad <<= 1;
            for (int t = tid; t < npad; t += 256) if (t >= n) buf[t] = make_uint2(0u, 0xFFFFFFFFu);
            __syncthreads();
            bitonic_sort_shared(buf, npad);
            use_buf = true;
            psel = (NPOSMAX < n) ? NPOSMAX : n;
        }
        for (int t = tid; t < psel; t += 256) {
            uint32_t packed = use_buf ? buf[t].y : plist[t].y;
            int i = (int)(packed & 0x1FFFFu);
            int orit = (int)(packed >> 17);
            int a = i % An, hw = i / An;
            float l = logits[(b * An + a) * HWn + hw];
            cls += fmaxf(l, 0.0f) - l + log1pf(expf(-fabsf(l)));   // BCE(l,1)
            float4 avx = ((const float4*)anchors)[b * Nn + i];
            float4 tv = ((const float4*)targets)[b * Mn + orit];
            float aws = avx.z - avx.x + 1.0f, ahs = avx.w - avx.y + 1.0f;
            float axc = avx.x + 0.5f * aws, ayc = avx.y + 0.5f * ahs;
            float tws = tv.z - tv.x + 1.0f, ths = tv.w - tv.y + 1.0f;
            float txc = tv.x + 0.5f * tws, tyc = tv.y + 0.5f * ths;
            float off0 = (txc - axc) / aws;
            float off1 = (tyc - ayc) / ahs;
            float off2 = logf(tws / aws);
            float off3 = logf(ths / ahs);
            float br0 = bregs[(b * 12 + a * 4 + 0) * HWn + hw];
            float br1 = bregs[(b * 12 + a * 4 + 1) * HWn + hw];
            float br2 = bregs[(b * 12 + a * 4 + 2) * HWn + hw];
            float br3 = bregs[(b * 12 + a * 4 + 3) * HWn + hw];
            float d;
            d = fabsf(br0 - off0); reg += (d < BETA) ? 0.5f * d * d / BETA : d - 0.5f * BETA;
            d = fabsf(br1 - off1); reg += (d < BETA) ? 0.5f * d * d / BETA : d - 0.5f * BETA;
            d = fabsf(br2 - off2); reg += (d < BETA) ? 0.5f * d * d / BETA : d - 0.5f * BETA;
            d = fabsf(br3 - off3); reg += (d < BETA) ? 0.5f * d * d / BETA : d - 0.5f * BETA;
        }
        __syncthreads();

        int need = (int)ws[OFF_NEED + b];
        if (need > 0) {
            uint32_t nbu = ws[OFF_BNDCNT + b];
            int nb = (nbu < (uint32_t)BND_CAP) ? (int)nbu : BND_CAP;
            const uint2* blist = (const uint2*)(ws + OFF_BLIST) + (size_t)b * BND_CAP;
            for (int t = tid; t < nb; t += 256) buf[t] = blist[t];
            int npad = 1; while (npad < nb) npad <<= 1;
            for (int t = tid; t < npad; t += 256) if (t >= nb) buf[t] = make_uint2(0u, 0xFFFFFFFFu);
            __syncthreads();
            bitonic_sort_shared(buf, npad);
            int sel = (need < nb) ? need : nb;
            for (int t = tid; t < sel; t += 256) {
                int i = (int)buf[t].y;
                int a = i % An, hw = i / An;
                float l = logits[(b * An + a) * HWn + hw];
                cls += fmaxf(l, 0.0f) + log1pf(expf(-fabsf(l)));   // BCE(l,0)
            }
        }

        red[tid] = cls;
        __syncthreads();
        for (int s = 128; s > 0; s >>= 1) {
            if (tid < s) red[tid] += red[tid + s];
            __syncthreads();
        }
        if (tid == 0 && red[0] != 0.0f) atomicAdd((float*)&ws[OFF_CLS], red[0]);
        __syncthreads();
        red[tid] = reg;
        __syncthreads();
        for (int s = 128; s > 0; s >>= 1) {
            if (tid < s) red[tid] += red[tid + s];
            __syncthreads();
        }
        if (tid == 0) {
            if (red[0] != 0.0f) atomicAdd((float*)&ws[OFF_REG], red[0]);
            __threadfence();
            uint32_t old = atomicAdd(&ws[OFF_DONE], 1u);
            if (old == Bn - 1) {
                float cls_tot = __uint_as_float(atomicAdd(&ws[OFF_CLS], 0u));
                float reg_tot = __uint_as_float(atomicAdd(&ws[OFF_REG], 0u));
                float cnt = (float)atomicAdd(&ws[OFF_COUNT], 0u);
                out[0] = cls_tot / cnt;
                out[1] = reg_tot / cnt;
            }
        }
    }
}

extern "C" void kernel_launch(void* const* d_in, const int* in_sizes, int n_in,
                              void* d_out, int out_size, void* d_ws, size_t ws_size,
                              hipStream_t stream) {
    const float* anchors = (const float*)d_in[0];   // [B, N, 4]
    const float* logits  = (const float*)d_in[1];   // [B, A, H, W]
    const float* bregs   = (const float*)d_in[2];   // [B, 4A, H, W]
    const float* sizes   = (const float*)d_in[3];   // [B, 2]
    const float* targets = (const float*)d_in[4];   // [B, M, 4]
    float* out = (float*)d_out;
    uint32_t* ws = (uint32_t*)d_ws;

    void* args[] = { (void*)&anchors, (void*)&targets, (void*)&sizes,
                     (void*)&logits, (void*)&bregs, (void*)&ws, (void*)&out };
    hipLaunchCooperativeKernel((const void*)fused, dim3(NBLK, Bn), dim3(256),
                               args, 0, stream);
}

// Round 2
// 158.083 us; speedup vs baseline: 2.2537x; 2.2537x over previous
//
#include <hip/hip_runtime.h>
#include <stdint.h>

#define Bn 4
#define An 3
#define Hn 168
#define Wn 256
#define Mn 32
#define HWn (Hn*Wn)
#define Nn (HWn*An)          // 129024
#define POS_CAP 8192
#define NPERIM 256
#define NPOSMAX 128
#define FG_THR 0.7f
#define BG_THR 0.3f
#define BETA (1.0f/9.0f)

#define NBLK 126             // blocks per image
#define APT 4                // anchors/thread
#define STRIDE (NBLK * 256)  // 32256
#define BUCKET_CAP 256       // per-bin bucket (expected ~40/bin)

// ---- workspace layout (uint32 word offsets; all uint2/uint4 bases aligned) ----
#define OFF_POSCNT 0            // Bn
#define OFF_COUNT  16           // 1
#define OFF_CLS    17           // 1 (float bits)
#define OFF_REG    18           // 1 (float bits)
#define OFF_DONE   19           // 1
#define OFF_KEYS   24           // Bn*2                        -> 32
#define OFF_PCM    32           // Bn*NBLK*Mn = 16128          -> 16160 (block colmax bits)
#define OFF_WPCM   16160        // Bn*NBLK*4*Mn = 64512        -> 80672 (wave colmax bits)
#define OFF_PLIST  80672        // Bn*POS_CAP*2 = 65536        -> 146208
#define OFF_BINCNT 146208       // Bn*1024 = 4096              -> 150304
#define OFF_BINBCE 150304       // Bn*1024 = 4096              -> 154400 (float bits)
#define OFF_REC    154400       // Bn*Nn*2 = 1032192           -> 1186592 (per-anchor records)
#define OFF_BUCKET 1186592      // Bn*1024*BUCKET_CAP*2 = 2097152 -> 3283744 (~13.1MB)

// ------------------- threefry2x32 (20 rounds) -------------------
__device__ __forceinline__ uint32_t rotl32(uint32_t v, int n) { return (v << n) | (v >> (32 - n)); }

__device__ __forceinline__ void tf2x32(uint32_t k0, uint32_t k1, uint32_t x0, uint32_t x1,
                                       uint32_t& o0, uint32_t& o1) {
    uint32_t k2 = k0 ^ k1 ^ 0x1BD11BDAu;
    x0 += k0; x1 += k1;
    x0 += x1; x1 = rotl32(x1, 13); x1 ^= x0;
    x0 += x1; x1 = rotl32(x1, 15); x1 ^= x0;
    x0 += x1; x1 = rotl32(x1, 26); x1 ^= x0;
    x0 += x1; x1 = rotl32(x1, 6);  x1 ^= x0;
    x0 += k1; x1 += k2 + 1u;
    x0 += x1; x1 = rotl32(x1, 17); x1 ^= x0;
    x0 += x1; x1 = rotl32(x1, 29); x1 ^= x0;
    x0 += x1; x1 = rotl32(x1, 16); x1 ^= x0;
    x0 += x1; x1 = rotl32(x1, 24); x1 ^= x0;
    x0 += k2; x1 += k0 + 2u;
    x0 += x1; x1 = rotl32(x1, 13); x1 ^= x0;
    x0 += x1; x1 = rotl32(x1, 15); x1 ^= x0;
    x0 += x1; x1 = rotl32(x1, 26); x1 ^= x0;
    x0 += x1; x1 = rotl32(x1, 6);  x1 ^= x0;
    x0 += k0; x1 += k1 + 3u;
    x0 += x1; x1 = rotl32(x1, 17); x1 ^= x0;
    x0 += x1; x1 = rotl32(x1, 29); x1 ^= x0;
    x0 += x1; x1 = rotl32(x1, 16); x1 ^= x0;
    x0 += x1; x1 = rotl32(x1, 24); x1 ^= x0;
    x0 += k1; x1 += k2 + 4u;
    x0 += x1; x1 = rotl32(x1, 13); x1 ^= x0;
    x0 += x1; x1 = rotl32(x1, 15); x1 ^= x0;
    x0 += x1; x1 = rotl32(x1, 26); x1 ^= x0;
    x0 += x1; x1 = rotl32(x1, 6);  x1 ^= x0;
    x0 += k2; x1 += k0 + 5u;
    o0 = x0; o1 = x1;
}

__device__ __forceinline__ uint32_t rng_m23(uint32_t k0, uint32_t k1, uint32_t i) {
    uint32_t o0, o1;
    tf2x32(k0, k1, 0u, i, o0, o1);
    return (o0 ^ o1) >> 9;
}

// ------------------- IoU (single definition) ------------
__device__ __forceinline__ float iou_one(float a0, float a1, float a2, float a3,
                                         float t0, float t1, float t2, float t3) {
    float xtl = fmaxf(a0, t0), ytl = fmaxf(a1, t1);
    float xrb = fminf(a2, t2), yrb = fminf(a3, t3);
    float iw = fmaxf(xrb - xtl + 1.0f, 0.0f);
    float ih = fmaxf(yrb - ytl + 1.0f, 0.0f);
    float inter = iw * ih;
    float area1 = (a2 - a0 + 1.0f) * (a3 - a1 + 1.0f);
    float area2 = (t2 - t0 + 1.0f) * (t3 - t1 + 1.0f);
    return inter * __builtin_amdgcn_rcpf(area1 + area2 - inter);
}

// ------------------- selection order (JAX top_k: larger priority first, tie -> smaller idx)
__device__ __forceinline__ bool sel_less(uint2 a, uint2 b) {
    return (a.x > b.x) || (a.x == b.x && a.y < b.y);
}

__device__ void bitonic_sort_shared(uint2* buf, int n) {   // n = pow2
    for (int k = 2; k <= n; k <<= 1) {
        for (int j = k >> 1; j > 0; j >>= 1) {
            for (int t = (int)threadIdx.x; t < n; t += 256) {
                int ixj = t ^ j;
                if (ixj > t) {
                    uint2 x = buf[t], y = buf[ixj];
                    bool up = ((t & k) == 0);
                    bool sw = up ? sel_less(y, x) : sel_less(x, y);
                    if (sw) { buf[t] = y; buf[ixj] = x; }
                }
            }
            __syncthreads();
        }
    }
}

// =====================================================================================
// K1: IoU pass. Writes per-anchor records {tie32, flags}, block colmax, wave colmax.
// restore (done in K2): iou==global_cm  <=>  iou==wave_max  AND  wave_max==global_cm
// (exact: identical fmaxf chains; verified bit-exact in previous rounds).
// =====================================================================================
__global__ void __launch_bounds__(256) k1_iou(const float* __restrict__ anchors,
                                              const float* __restrict__ targets,
                                              const float* __restrict__ sizes,
                                              uint32_t* __restrict__ ws) {
    const int b = blockIdx.y, j = blockIdx.x, tid = threadIdx.x;
    const int wid = tid >> 6, lane = tid & 63;

    // folded init (block 0,0): control words + bin counters/bce + RNG keys
    if (b == 0 && j == 0) {
        if (tid < 24) ws[tid] = 0u;
        for (int q = tid; q < 2 * Bn * 1024; q += 256) ws[OFF_BINCNT + q] = 0u;
        if (tid == 0) {
            for (int bb = 0; bb < Bn; ++bb) {
                uint32_t o0, o1;
                tf2x32(0u, 42u, 0u, (uint32_t)bb, o0, o1);
                ws[OFF_KEYS + 2*bb] = o0; ws[OFF_KEYS + 2*bb + 1] = o1;
            }
        }
    }

    __shared__ float part[4][Mn];
    const int base = j * 256 + tid;
    float4 av[APT];
    #pragma unroll
    for (int k = 0; k < APT; ++k)
        av[k] = ((const float4*)anchors)[b * Nn + base + k * STRIDE];

    float rowmax[APT]; int ori[APT]; uint32_t tie[APT];
    #pragma unroll
    for (int k = 0; k < APT; ++k) { rowmax[k] = -1.0f; ori[k] = 0; tie[k] = 0u; }

    float mycm = 0.0f;   // lane t holds wave colmax for target t (t<32)
    #pragma unroll 4
    for (int t = 0; t < Mn; ++t) {
        float4 tv = ((const float4*)targets)[b * Mn + t];
        float io[APT];
        float m0 = 0.0f;
        #pragma unroll
        for (int k = 0; k < APT; ++k) {
            io[k] = iou_one(av[k].x, av[k].y, av[k].z, av[k].w, tv.x, tv.y, tv.z, tv.w);
            if (io[k] > rowmax[k]) { rowmax[k] = io[k]; ori[k] = t; }
            m0 = fmaxf(m0, io[k]);
        }
        #pragma unroll
        for (int o = 32; o > 0; o >>= 1) m0 = fmaxf(m0, __shfl_xor(m0, o, 64));
        if (lane == t) mycm = m0;
        #pragma unroll
        for (int k = 0; k < APT; ++k)
            tie[k] |= (io[k] == m0) ? (1u << t) : 0u;
    }

    // wave colmax -> global (coalesced, one store per lane<32)
    if (lane < Mn)
        ws[OFF_WPCM + (((size_t)b * NBLK + j) * 4 + wid) * 32 + lane] = __float_as_uint(mycm);
    // block colmax via LDS
    if (lane < Mn) part[wid][lane] = mycm;
    __syncthreads();
    if (tid < Mn) {
        float v = fmaxf(fmaxf(part[0][tid], part[1][tid]),
                        fmaxf(part[2][tid], part[3][tid]));
        ws[OFF_PCM + ((size_t)b * NBLK + j) * Mn + tid] = __float_as_uint(v);
    }

    // per-anchor records
    const float sh = sizes[b * 2 + 0], sw = sizes[b * 2 + 1];
    #pragma unroll
    for (int k = 0; k < APT; ++k) {
        bool inside = (av[k].x >= 0.0f) && (av[k].y >= 0.0f) &&
                      (av[k].z <= sw - 1.0f) && (av[k].w <= sh - 1.0f);
        uint32_t fl = (uint32_t)ori[k]
                    | (inside ? 32u : 0u)
                    | (rowmax[k] >= FG_THR ? 64u : 0u)
                    | (rowmax[k] < BG_THR ? 128u : 0u);
        ((uint2*)(ws + OFF_REC))[(size_t)b * Nn + base + k * STRIDE] =
            make_uint2(tie[k], fl);
    }
}

// =====================================================================================
// K2: decode records + RNG + positives PLIST + negatives -> per-bin {count, BCE sum}
// and per-bin bucket scatter. No IoU recompute, no anchor reload.
// =====================================================================================
__global__ void __launch_bounds__(256) k2_cat(const float* __restrict__ logits,
                                              uint32_t* __restrict__ ws) {
    const int b = blockIdx.y, j = blockIdx.x, tid = threadIdx.x;
    const int wid = tid >> 6, lane = tid & 63;
    __shared__ float cmf[Mn];
    __shared__ float redf[256];

    // reduce per-block colmax -> global colmax (exact: max assoc/comm)
    {
        int t = tid & 31, sub = tid >> 5;
        float acc = 0.0f;
        for (int jj = sub; jj < NBLK; jj += 8)
            acc = fmaxf(acc, __uint_as_float(ws[OFF_PCM + ((size_t)b * NBLK + jj) * Mn + t]));
        redf[tid] = acc;
        __syncthreads();
        if (sub == 0) {
            #pragma unroll
            for (int q = 1; q < 8; ++q) acc = fmaxf(acc, redf[t + 32 * q]);
            cmf[t] = acc;
        }
    }
    __syncthreads();

    uint32_t eqmask;   // bit t: this wave's colmax[t] == global colmax[t]
    {
        bool eq = false;
        if (lane < Mn)
            eq = (ws[OFF_WPCM + (((size_t)b * NBLK + j) * 4 + wid) * 32 + lane]
                  == __float_as_uint(cmf[lane]));
        eqmask = (uint32_t)__ballot(eq);
    }

    const int base = j * 256 + tid;
    const uint32_t key0 = ws[OFF_KEYS + 2 * b], key1 = ws[OFF_KEYS + 2 * b + 1];
    unsigned long long lt_mask = (lane == 63) ? 0x7FFFFFFFFFFFFFFFull
                                              : ((1ull << lane) - 1ull);
    #pragma unroll
    for (int k = 0; k < APT; ++k) {
        const int i = base + k * STRIDE;
        uint2 rec = ((const uint2*)(ws + OFF_REC))[(size_t)b * Nn + i];
        bool restore = (rec.x & eqmask) != 0u;
        uint32_t fl = rec.y;
        uint32_t cat = 0;
        if (fl & 32u) {
            if (restore || (fl & 64u)) cat = 2;
            else if (fl & 128u) cat = 1;
        }
        uint32_t m = rng_m23(key0, key1, (uint32_t)i);
        // positives: wave-aggregated global ticket (rare)
        unsigned long long pmask = __ballot(cat == 2u);
        if (pmask) {
            int leader = __ffsll((long long)pmask) - 1;
            uint32_t bb = 0;
            if (lane == leader) bb = atomicAdd(&ws[OFF_POSCNT + b], (uint32_t)__popcll(pmask));
            bb = __shfl(bb, leader, 64);
            if (cat == 2u) {
                uint32_t p = bb + (uint32_t)__popcll(pmask & lt_mask);
                if (p < POS_CAP)
                    ((uint2*)(ws + OFF_PLIST))[(size_t)b * POS_CAP + p] =
                        make_uint2(m, (uint32_t)i | ((fl & 31u) << 17));
            }
        }
        // negatives: bin count + immediate BCE accumulation + bucket scatter
        if (cat == 1u) {
            int bin = (int)(m >> 13);
            uint32_t slot = atomicAdd(&ws[OFF_BINCNT + (b << 10) + bin], 1u);
            if (slot < BUCKET_CAP)
                ((uint2*)(ws + OFF_BUCKET))[((((size_t)b << 10) + bin) << 8) + slot] =
                    make_uint2(m, (uint32_t)i);
            int a = i % An, hw = i / An;
            float l = logits[(b * An + a) * HWn + hw];
            atomicAdd((float*)&ws[OFF_BINBCE + (b << 10) + bin],
                      fmaxf(l, 0.0f) + log1pf(expf(-fabsf(l))));   // BCE(l,0)
        }
    }
}

// =====================================================================================
// K3: per-image finalize. Suffix-scan bin counts -> boundary bin; add per-bin BCE sums
// for fully-included bins; sort only the boundary bin's ~40 entries; positives epilogue.
// =====================================================================================
__global__ void __launch_bounds__(256) k3_final(const float* __restrict__ anchors,
                                                const float* __restrict__ targets,
                                                const float* __restrict__ logits,
                                                const float* __restrict__ bregs,
                                                uint32_t* __restrict__ ws,
                                                float* __restrict__ out) {
    const int b = blockIdx.x, tid = threadIdx.x;
    __shared__ union { uint32_t csum[256]; uint2 buf[2048]; } sh;
    __shared__ float red[256];
    __shared__ int s_bd, s_need;
    float cls = 0.0f, reg = 0.0f;

    // bin counts suffix scan
    uint4 hc = ((const uint4*)(ws + OFF_BINCNT + (b << 10)))[tid];
    uint32_t sum = hc.x + hc.y + hc.z + hc.w;
    sh.csum[tid] = sum;
    __syncthreads();
    for (int off = 1; off < 256; off <<= 1) {
        uint32_t mine = sh.csum[tid];
        uint32_t add = (tid + off < 256) ? sh.csum[tid + off] : 0u;
        __syncthreads();
        sh.csum[tid] = mine + add;
        __syncthreads();
    }
    uint32_t pc = ws[OFF_POSCNT + b];
    int num_pos = (pc < (uint32_t)NPOSMAX) ? (int)pc : NPOSMAX;
    int k_neg = NPERIM - num_pos;
    uint32_t total = sh.csum[0];
    if ((int)total < k_neg) {
        if (tid == 0) { s_bd = -1; s_need = 0; }
    } else {
        uint32_t incl = sh.csum[tid];
        uint32_t next = (tid < 255) ? sh.csum[tid + 1] : 0u;
        if ((int)incl >= k_neg && (int)next < k_neg) {
            int cum = (int)next;
            uint32_t hv[4] = { hc.x, hc.y, hc.z, hc.w };
            int boundary = -1, needed = 0;
            #pragma unroll
            for (int q = 3; q >= 0; --q) {
                int c = (int)hv[q];
                if (cum + c >= k_neg) { boundary = 4 * tid + q; needed = k_neg - cum; break; }
                cum += c;
            }
            s_bd = boundary; s_need = needed;
        }
    }
    if (tid == 0) {
        int sel_negs = ((int)total < k_neg) ? (int)total : k_neg;
        atomicAdd(&ws[OFF_COUNT], (uint32_t)(num_pos + sel_negs));
    }
    __syncthreads();
    const int bd = s_bd, need = s_need;

    // fully-included bins: add per-bin BCE sums
    {
        float4 hb = ((const float4*)(ws + OFF_BINBCE + (b << 10)))[tid];
        int bin0 = 4 * tid;
        if (bin0 + 0 > bd) cls += hb.x;
        if (bin0 + 1 > bd) cls += hb.y;
        if (bin0 + 2 > bd) cls += hb.z;
        if (bin0 + 3 > bd) cls += hb.w;
    }
    __syncthreads();   // csum dead; buf reuse begins

    // boundary bin: sort its entries, take top-`need`
    if (need > 0) {
        int cnt = (int)ws[OFF_BINCNT + (b << 10) + bd];
        if (cnt > BUCKET_CAP) cnt = BUCKET_CAP;
        const uint2* bkt = (const uint2*)(ws + OFF_BUCKET) + ((((size_t)b << 10) + bd) << 8);
        for (int t = tid; t < cnt; t += 256) sh.buf[t] = bkt[t];
        int npad = 1; while (npad < cnt) npad <<= 1;
        for (int t = tid; t < npad; t += 256) if (t >= cnt) sh.buf[t] = make_uint2(0u, 0xFFFFFFFFu);
        __syncthreads();
        bitonic_sort_shared(sh.buf, npad);
        int sel = (need < cnt) ? need : cnt;
        for (int t = tid; t < sel; t += 256) {
            int i = (int)sh.buf[t].y;
            int a = i % An, hw = i / An;
            float l = logits[(b * An + a) * HWn + hw];
            cls += fmaxf(l, 0.0f) + log1pf(expf(-fabsf(l)));   // BCE(l,0)
        }
    }
    __syncthreads();

    // positives
    {
        int pci = (pc < (uint32_t)POS_CAP) ? (int)pc : POS_CAP;
        const uint2* plist = (const uint2*)(ws + OFF_PLIST) + (size_t)b * POS_CAP;
        int psel = (pci < NPOSMAX) ? pci : NPOSMAX;
        bool use_buf = false;
        if (pci > NPOSMAX) {
            int n = (pci < 2048) ? pci : 2048;
            for (int t = tid; t < n; t += 256) sh.buf[t] = plist[t];
            int npad = 1; while (npad < n) npad <<= 1;
            for (int t = tid; t < npad; t += 256) if (t >= n) sh.buf[t] = make_uint2(0u, 0xFFFFFFFFu);
            __syncthreads();
            bitonic_sort_shared(sh.buf, npad);
            use_buf = true;
            psel = (NPOSMAX < n) ? NPOSMAX : n;
        }
        for (int t = tid; t < psel; t += 256) {
            uint32_t packed = use_buf ? sh.buf[t].y : plist[t].y;
            int i = (int)(packed & 0x1FFFFu);
            int orit = (int)(packed >> 17);
            int a = i % An, hw = i / An;
            float l = logits[(b * An + a) * HWn + hw];
            cls += fmaxf(l, 0.0f) - l + log1pf(expf(-fabsf(l)));   // BCE(l,1)
            float4 avx = ((const float4*)anchors)[b * Nn + i];
            float4 tv = ((const float4*)targets)[b * Mn + orit];
            float aws = avx.z - avx.x + 1.0f, ahs = avx.w - avx.y + 1.0f;
            float axc = avx.x + 0.5f * aws, ayc = avx.y + 0.5f * ahs;
            float tws = tv.z - tv.x + 1.0f, ths = tv.w - tv.y + 1.0f;
            float txc = tv.x + 0.5f * tws, tyc = tv.y + 0.5f * ths;
            float off0 = (txc - axc) / aws;
            float off1 = (tyc - ayc) / ahs;
            float off2 = logf(tws / aws);
            float off3 = logf(ths / ahs);
            float br0 = bregs[(b * 12 + a * 4 + 0) * HWn + hw];
            float br1 = bregs[(b * 12 + a * 4 + 1) * HWn + hw];
            float br2 = bregs[(b * 12 + a * 4 + 2) * HWn + hw];
            float br3 = bregs[(b * 12 + a * 4 + 3) * HWn + hw];
            float d;
            d = fabsf(br0 - off0); reg += (d < BETA) ? 0.5f * d * d / BETA : d - 0.5f * BETA;
            d = fabsf(br1 - off1); reg += (d < BETA) ? 0.5f * d * d / BETA : d - 0.5f * BETA;
            d = fabsf(br2 - off2); reg += (d < BETA) ? 0.5f * d * d / BETA : d - 0.5f * BETA;
            d = fabsf(br3 - off3); reg += (d < BETA) ? 0.5f * d * d / BETA : d - 0.5f * BETA;
        }
    }

    // reductions + cross-image epilogue
    red[tid] = cls;
    __syncthreads();
    for (int s = 128; s > 0; s >>= 1) {
        if (tid < s) red[tid] += red[tid + s];
        __syncthreads();
    }
    if (tid == 0 && red[0] != 0.0f) atomicAdd((float*)&ws[OFF_CLS], red[0]);
    __syncthreads();
    red[tid] = reg;
    __syncthreads();
    for (int s = 128; s > 0; s >>= 1) {
        if (tid < s) red[tid] += red[tid + s];
        __syncthreads();
    }
    if (tid == 0) {
        if (red[0] != 0.0f) atomicAdd((float*)&ws[OFF_REG], red[0]);
        __threadfence();
        uint32_t old = atomicAdd(&ws[OFF_DONE], 1u);
        if (old == Bn - 1) {
            float cls_tot = __uint_as_float(atomicAdd(&ws[OFF_CLS], 0u));
            float reg_tot = __uint_as_float(atomicAdd(&ws[OFF_REG], 0u));
            float cnt = (float)atomicAdd(&ws[OFF_COUNT], 0u);
            out[0] = cls_tot / cnt;
            out[1] = reg_tot / cnt;
        }
    }
}

extern "C" void kernel_launch(void* const* d_in, const int* in_sizes, int n_in,
                              void* d_out, int out_size, void* d_ws, size_t ws_size,
                              hipStream_t stream) {
    const float* anchors = (const float*)d_in[0];   // [B, N, 4]
    const float* logits  = (const float*)d_in[1];   // [B, A, H, W]
    const float* bregs   = (const float*)d_in[2];   // [B, 4A, H, W]
    const float* sizes   = (const float*)d_in[3];   // [B, 2]
    const float* targets = (const float*)d_in[4];   // [B, M, 4]
    float* out = (float*)d_out;
    uint32_t* ws = (uint32_t*)d_ws;

    k1_iou<<<dim3(NBLK, Bn), dim3(256), 0, stream>>>(anchors, targets, sizes, ws);
    k2_cat<<<dim3(NBLK, Bn), dim3(256), 0, stream>>>(logits, ws);
    k3_final<<<dim3(Bn), dim3(256), 0, stream>>>(anchors, targets, logits, bregs, ws, out);
}